// Round 1
// baseline (6298.526 us; speedup 1.0000x reference)
//
#include <hip/hip_runtime.h>

typedef _Float16 f16;
typedef _Float16 f16x8 __attribute__((ext_vector_type(8)));
typedef _Float16 f16x4 __attribute__((ext_vector_type(4)));
typedef float f32x4 __attribute__((ext_vector_type(4)));

#define MFMA16(a, b, c) __builtin_amdgcn_mfma_f32_16x16x32_f16(a, b, c, 0, 0, 0)

__device__ __forceinline__ float fast_tanh(float x) {
    // tanh(x) = 1 - 2/(1+exp2(2*log2(e)*x)); exact saturation at +-inf
    float e = __builtin_amdgcn_exp2f(x * 2.885390081777927f);
    return 1.0f - 2.0f * __builtin_amdgcn_rcpf(e + 1.0f);
}

// ---------------- weight convert: f32 -> f16, vectorized x4 ----------------
__global__ void cvt_kernel(const float* __restrict__ src, f16* __restrict__ dst, const int n4) {
    const int i = blockIdx.x * blockDim.x + threadIdx.x;
    if (i < n4) {
        const float4 v = ((const float4*)src)[i];
        f16x4 o = { (f16)v.x, (f16)v.y, (f16)v.z, (f16)v.w };
        *(f16x4*)(dst + (size_t)i * 4) = o;
    }
}

__global__ void bias_combine_kernel(const float* __restrict__ b_ih, const float* __restrict__ b_hh,
                                    float* __restrict__ bias_c) {
    const int i = blockIdx.x * blockDim.x + threadIdx.x;
    if (i < 6 * 384) bias_c[i] = b_ih[i] + b_hh[i];
}

// ---------------- embedding gather + cast: seq0[t][b][e] f16 ----------------
__global__ void embed_kernel(const int* __restrict__ x, const float* __restrict__ emb,
                             f16* __restrict__ seq0) {
    const int token = blockIdx.x;          // token = s*16 + b
    const int s = token >> 4, b = token & 15;
    const int idx = x[b * 512 + s];
    const float4 v = ((const float4*)(emb + (size_t)idx * 256))[threadIdx.x]; // 64 thr * 4
    f16x4 o = { (f16)v.x, (f16)v.y, (f16)v.z, (f16)v.w };
    *(f16x4*)(seq0 + (size_t)token * 256 + threadIdx.x * 4) = o;
}

// ---------------- per-layer input projection -----------------------------
// pre[t][tile][lane][r] = seq[t*16+b][:] . Wi[n][:] + (b_ih+b_hh)[n]
// MFMA tiling: M-tile = t (rows b=0..15), 24 N-tiles over H=384, 4 waves x 6 tiles.
__global__ __launch_bounds__(256) void input_proj_kernel(
    const f16* __restrict__ seq,    // [8192][K]
    const f16* __restrict__ Wi,     // [384][K]
    const float* __restrict__ bias, // [384] combined b_ih+b_hh
    float* __restrict__ pre,        // [512][24][64][4]
    const int K) {
    const int tid = threadIdx.x, lane = tid & 63, w = tid >> 6;
    const int lr = lane & 15, lq = lane >> 4, kb = lq * 8;
    const int t = blockIdx.x;

    f32x4 acc[6];
#pragma unroll
    for (int i = 0; i < 6; ++i) {
        const float bv = bias[(w * 6 + i) * 16 + lr];
        acc[i] = (f32x4){ bv, bv, bv, bv };
    }
    const f16* arow = seq + (size_t)(t * 16 + lr) * K + kb;
    const int nk = K >> 5;
    for (int kk = 0; kk < nk; ++kk) {
        const f16x8 a = *(const f16x8*)(arow + kk * 32);
#pragma unroll
        for (int i = 0; i < 6; ++i) {
            const f16x8 b = *(const f16x8*)(Wi + (size_t)((w * 6 + i) * 16 + lr) * K + kk * 32 + kb);
            acc[i] = MFMA16(a, b, acc[i]);
        }
    }
    float* pp = pre + ((size_t)(t * 24 + w * 6) * 64 + lane) * 4;
#pragma unroll
    for (int i = 0; i < 6; ++i) *(f32x4*)(pp + i * 256) = acc[i];
}

// ---------------- recurrent scan: one workgroup, Wh register-resident -----
// h_t = tanh(pre_t + h_{t-1} Wh^T). 4 waves x 6 N-tiles, K=384 (12 kfrags).
// h double-buffered in LDS, padded stride 392 to dodge bank conflicts.
__global__ __launch_bounds__(256, 1) void scan_kernel(
    const float* __restrict__ pre,  // [512][24][64][4]
    const f16* __restrict__ Wh,     // [384][384]
    f16* __restrict__ seq_out) {    // [8192][384]
    __shared__ f16 hbuf[2][16][392];
    const int tid = threadIdx.x;
    const int lane = tid & 63;
    const int w = tid >> 6;
    const int lr = lane & 15;
    const int lq = lane >> 4;
    const int kb = lq * 8;

    for (int i = tid; i < 2 * 16 * 392; i += 256) (&hbuf[0][0][0])[i] = (f16)0.0f;

    // preload Wh fragments: wave w owns N-tiles w*6 .. w*6+5  (288 regs/lane)
    f16x8 Bf[6][12];
#pragma unroll
    for (int i = 0; i < 6; ++i) {
        const f16* wrow = Wh + (size_t)((w * 6 + i) * 16 + lr) * 384 + kb;
#pragma unroll
        for (int kk = 0; kk < 12; ++kk) Bf[i][kk] = *(const f16x8*)(wrow + kk * 32);
    }

    __syncthreads();

    f32x4 pnxt[6];
    {
        const float* pp = pre + ((size_t)(w * 6) * 64 + lane) * 4;
#pragma unroll
        for (int i = 0; i < 6; ++i) pnxt[i] = *(const f32x4*)(pp + i * 256);
    }

    for (int t = 0; t < 512; ++t) {
        f32x4 pcur[6];
#pragma unroll
        for (int i = 0; i < 6; ++i) pcur[i] = pnxt[i];
        {   // software-prefetch next step's pre (hides L2/L3 latency under MFMA)
            const int t2 = (t < 511) ? (t + 1) : 511;
            const float* pp = pre + ((size_t)(t2 * 24 + w * 6) * 64 + lane) * 4;
#pragma unroll
            for (int i = 0; i < 6; ++i) pnxt[i] = *(const f32x4*)(pp + i * 256);
        }

        f32x4 acc[6];
#pragma unroll
        for (int i = 0; i < 6; ++i) acc[i] = (f32x4){ 0.f, 0.f, 0.f, 0.f };

        const f16* hb = &hbuf[t & 1][0][0] + lr * 392 + kb;
#pragma unroll
        for (int kk = 0; kk < 12; ++kk) {
            const f16x8 a = *(const f16x8*)(hb + kk * 32);
#pragma unroll
            for (int i = 0; i < 6; ++i) acc[i] = MFMA16(a, Bf[i][kk], acc[i]);
        }

        f16* hn = &hbuf[(t + 1) & 1][0][0];
#pragma unroll
        for (int i = 0; i < 6; ++i) {
            const int n = (w * 6 + i) * 16 + lr;
#pragma unroll
            for (int r = 0; r < 4; ++r) {
                const int b = lq * 4 + r;
                const float v = acc[i][r] + pcur[i][r];
                const f16 hv = (f16)fast_tanh(v);
                hn[b * 392 + n] = hv;
                seq_out[(size_t)(t * 16 + b) * 384 + n] = hv;
            }
        }
        __syncthreads();
    }
}

// ---------------- output projection: [8192x384] x [384x32000] + bias -----
// 128x128 tile, BK=32, 4 waves (2x2), wave tile 64x64.
__global__ __launch_bounds__(256) void out_proj_kernel(
    const f16* __restrict__ A,      // [8192][384] final hidden
    const f16* __restrict__ Bm,     // [32000][384] W_out f16
    const float* __restrict__ bias, // [32000]
    float* __restrict__ C) {        // [16][512][32000]
    __shared__ f16 As[128][40];
    __shared__ f16 Bs[128][40];
    const int tid = threadIdx.x, lane = tid & 63, w = tid >> 6;
    const int lr = lane & 15, lq = lane >> 4;
    const int bm = blockIdx.x, bn = blockIdx.y;
    const int wm = w >> 1, wn = w & 1;

    f32x4 acc[4][4];
#pragma unroll
    for (int i = 0; i < 4; ++i)
#pragma unroll
        for (int j = 0; j < 4; ++j) acc[i][j] = (f32x4){ 0.f, 0.f, 0.f, 0.f };

    const int sr = tid >> 1, sh = tid & 1;
    const f16* Ag = A + (size_t)(bm * 128 + sr) * 384 + sh * 16;
    const f16* Bg = Bm + (size_t)(bn * 128 + sr) * 384 + sh * 16;

    for (int kt = 0; kt < 12; ++kt) {
        const f16x8 a0 = *(const f16x8*)(Ag + kt * 32);
        const f16x8 a1 = *(const f16x8*)(Ag + kt * 32 + 8);
        const f16x8 b0 = *(const f16x8*)(Bg + kt * 32);
        const f16x8 b1 = *(const f16x8*)(Bg + kt * 32 + 8);
        *(f16x8*)(&As[sr][sh * 16]) = a0;
        *(f16x8*)(&As[sr][sh * 16 + 8]) = a1;
        *(f16x8*)(&Bs[sr][sh * 16]) = b0;
        *(f16x8*)(&Bs[sr][sh * 16 + 8]) = b1;
        __syncthreads();
        f16x8 af[4], bf[4];
#pragma unroll
        for (int mi = 0; mi < 4; ++mi) af[mi] = *(const f16x8*)(&As[wm * 64 + mi * 16 + lr][lq * 8]);
#pragma unroll
        for (int ni = 0; ni < 4; ++ni) bf[ni] = *(const f16x8*)(&Bs[wn * 64 + ni * 16 + lr][lq * 8]);
#pragma unroll
        for (int mi = 0; mi < 4; ++mi)
#pragma unroll
            for (int ni = 0; ni < 4; ++ni) acc[mi][ni] = MFMA16(af[mi], bf[ni], acc[mi][ni]);
        __syncthreads();
    }

    float bv[4];
#pragma unroll
    for (int ni = 0; ni < 4; ++ni) bv[ni] = bias[bn * 128 + wn * 64 + ni * 16 + lr];
#pragma unroll
    for (int mi = 0; mi < 4; ++mi) {
#pragma unroll
        for (int rr = 0; rr < 4; ++rr) {
            const int m = bm * 128 + wm * 64 + mi * 16 + lq * 4 + rr; // token = s*16+b
            const int s = m >> 4, b = m & 15;
            float* crow = C + (size_t)(b * 512 + s) * 32000;
#pragma unroll
            for (int ni = 0; ni < 4; ++ni) {
                const int n = bn * 128 + wn * 64 + ni * 16 + lr;
                crow[n] = acc[mi][ni][rr] + bv[ni];
            }
        }
    }
}

extern "C" void kernel_launch(void* const* d_in, const int* in_sizes, int n_in,
                              void* d_out, int out_size, void* d_ws, size_t ws_size,
                              hipStream_t stream) {
    const int* x = (const int*)d_in[0];
    const float* emb = (const float*)d_in[1];
    const float* W_ih0 = (const float*)d_in[2];
    const float* W_ih = (const float*)d_in[3];
    const float* W_hh = (const float*)d_in[4];
    const float* b_ih = (const float*)d_in[5];
    const float* b_hh = (const float*)d_in[6];
    const float* W_out = (const float*)d_in[7];
    const float* b_out = (const float*)d_in[8];
    float* out = (float*)d_out;

    // workspace layout (bytes)
    char* ws = (char*)d_ws;
    f16* Wi0_h = (f16*)(ws + 0);           //   384*256*2 = 196608
    f16* Wi_h = (f16*)(ws + 196608);       // 5*384*384*2 = 1474560
    f16* Wh_h = (f16*)(ws + 1671168);      // 6*384*384*2 = 1769472
    f16* Wout_h = (f16*)(ws + 3440640);    // 32000*384*2 = 24576000
    float* bias_c = (float*)(ws + 28016640); // 6*384*4 = 9216
    f16* seq0 = (f16*)(ws + 28025856);     // 8192*256*2 = 4194304
    f16* sA = (f16*)(ws + 32220160);       // 8192*384*2 = 6291456
    f16* sB = (f16*)(ws + 38511616);       // 8192*384*2 = 6291456
    float* pre = (float*)(ws + 44803072);  // 512*24*64*4*4 = 12582912  -> end 57385984
    if (ws_size < 57385984) return;

    cvt_kernel<<<96, 256, 0, stream>>>(W_ih0, Wi0_h, 24576);
    cvt_kernel<<<720, 256, 0, stream>>>(W_ih, Wi_h, 184320);
    cvt_kernel<<<864, 256, 0, stream>>>(W_hh, Wh_h, 221184);
    cvt_kernel<<<12000, 256, 0, stream>>>(W_out, Wout_h, 3072000);
    bias_combine_kernel<<<9, 256, 0, stream>>>(b_ih, b_hh, bias_c);
    embed_kernel<<<8192, 64, 0, stream>>>(x, emb, seq0);

    const f16* cur = seq0;
    f16* bufs[2] = { sA, sB };
    for (int l = 0; l < 6; ++l) {
        const f16* Wi = (l == 0) ? Wi0_h : (Wi_h + (size_t)(l - 1) * 384 * 384);
        const int K = (l == 0) ? 256 : 384;
        input_proj_kernel<<<512, 256, 0, stream>>>(cur, Wi, bias_c + l * 384, pre, K);
        f16* nxt = bufs[l & 1];
        scan_kernel<<<1, 256, 0, stream>>>(pre, Wh_h + (size_t)l * 384 * 384, nxt);
        cur = nxt;
    }
    dim3 g(64, 250);
    out_proj_kernel<<<g, 256, 0, stream>>>(cur, Wout_h, b_out, out);
}

// Round 2
// 2303.512 us; speedup vs baseline: 2.7343x; 2.7343x over previous
//
#include <hip/hip_runtime.h>

typedef _Float16 f16;
typedef _Float16 f16x8 __attribute__((ext_vector_type(8)));
typedef _Float16 f16x4 __attribute__((ext_vector_type(4)));
typedef float f32x4 __attribute__((ext_vector_type(4)));

#define MFMA16(a, b, c) __builtin_amdgcn_mfma_f32_16x16x32_f16(a, b, c, 0, 0, 0)

__device__ __forceinline__ float fast_tanh(float x) {
    float e = __builtin_amdgcn_exp2f(x * 2.885390081777927f);
    return 1.0f - 2.0f * __builtin_amdgcn_rcpf(e + 1.0f);
}

// ---------------- flag sync (cross-block, agent scope) ----------------
__device__ __forceinline__ void wait_flag(const int* f, int target) {
    if (threadIdx.x == 0) {
        while (__hip_atomic_load(f, __ATOMIC_ACQUIRE, __HIP_MEMORY_SCOPE_AGENT) < target) {
            __builtin_amdgcn_s_sleep(2);
        }
    }
    __syncthreads();
}
__device__ __forceinline__ void set_flag(int* f, int val) {
    __syncthreads();  // all waves' stores drained (vmcnt 0) before release
    if (threadIdx.x == 0)
        __hip_atomic_store(f, val, __ATOMIC_RELEASE, __HIP_MEMORY_SCOPE_AGENT);
}

// ---------------- weight convert: f32 -> f16 ----------------
__global__ void cvt_kernel(const float* __restrict__ src, f16* __restrict__ dst, const int n4) {
    const int i = blockIdx.x * blockDim.x + threadIdx.x;
    if (i < n4) {
        const float4 v = ((const float4*)src)[i];
        f16x4 o = { (f16)v.x, (f16)v.y, (f16)v.z, (f16)v.w };
        *(f16x4*)(dst + (size_t)i * 4) = o;
    }
}

__global__ void bias_combine_kernel(const float* __restrict__ b_ih, const float* __restrict__ b_hh,
                                    float* __restrict__ bias_c) {
    const int i = blockIdx.x * blockDim.x + threadIdx.x;
    if (i < 6 * 384) bias_c[i] = b_ih[i] + b_hh[i];
}

// ---------------- embedding gather + cast ----------------
__global__ void embed_kernel(const int* __restrict__ x, const float* __restrict__ emb,
                             f16* __restrict__ seq0) {
    const int token = blockIdx.x;          // token = t*16 + b
    const int s = token >> 4, b = token & 15;
    const int idx = x[b * 512 + s];
    const float4 v = ((const float4*)(emb + (size_t)idx * 256))[threadIdx.x];
    f16x4 o = { (f16)v.x, (f16)v.y, (f16)v.z, (f16)v.w };
    *(f16x4*)(seq0 + (size_t)token * 256 + threadIdx.x * 4) = o;
}

// ---------------- A-role: input projection, Wi register-resident ----------------
// per chunk c (4 steps): preR[s][tile] = x_t . Wi^T + (b_ih+b_hh)   -> pre ring slot
template<int NK>
__device__ __forceinline__ void a_role(const f16* __restrict__ in_seq,
                                       const f16* __restrict__ Wi,
                                       const float* __restrict__ bias,
                                       float* __restrict__ preL,
                                       const int* flag_in, int* flag_pre, const int* flag_seq,
                                       const int L) {
    const int tid = threadIdx.x, lane = tid & 63, w = tid >> 6;
    const int lr = lane & 15, lq = lane >> 4;
    const int KIN = NK * 32;

    f16x8 WiF[6][NK];
#pragma unroll
    for (int i = 0; i < 6; ++i) {
        const f16* wrow = Wi + (size_t)((w * 6 + i) * 16 + lr) * KIN + lq * 8;
#pragma unroll
        for (int kk = 0; kk < NK; ++kk) WiF[i][kk] = *(const f16x8*)(wrow + kk * 32);
    }
    float bv[6];
#pragma unroll
    for (int i = 0; i < 6; ++i) bv[i] = bias[(w * 6 + i) * 16 + lr];

    for (int c = 0; c < 128; ++c) {
        if (L > 0) wait_flag(flag_in, c + 1);          // input chunk ready
        if (c >= 4) wait_flag(flag_seq, c - 3);        // ring back-pressure (B consumed slot)

        f32x4 acc[4][6];
#pragma unroll
        for (int s = 0; s < 4; ++s)
#pragma unroll
            for (int i = 0; i < 6; ++i) acc[s][i] = (f32x4){ bv[i], bv[i], bv[i], bv[i] };

        const int t0 = c * 4;
#pragma unroll
        for (int kk = 0; kk < NK; ++kk) {
            f16x8 a[4];
#pragma unroll
            for (int s = 0; s < 4; ++s)
                a[s] = *(const f16x8*)(in_seq + (size_t)((t0 + s) * 16 + lr) * KIN + kk * 32 + lq * 8);
#pragma unroll
            for (int s = 0; s < 4; ++s)
#pragma unroll
                for (int i = 0; i < 6; ++i) acc[s][i] = MFMA16(a[s], WiF[i][kk], acc[s][i]);
        }
        float* slot = preL + (c & 3) * 24576;
#pragma unroll
        for (int s = 0; s < 4; ++s)
#pragma unroll
            for (int i = 0; i < 6; ++i)
                *(f32x4*)(slot + ((size_t)(s * 24 + w * 6 + i) * 64 + lane) * 4) = acc[s][i];
        set_flag(flag_pre, c + 1);
    }
}

// ---------------- B-role: recurrence, Wh register-resident ----------------
__device__ __forceinline__ void b_role(const float* __restrict__ preL,
                                       const f16* __restrict__ Wh,
                                       f16* __restrict__ out_seq,
                                       const int* flag_pre, int* flag_seq,
                                       f16 (*hbuf)[16][392]) {
    const int tid = threadIdx.x, lane = tid & 63, w = tid >> 6;
    const int lr = lane & 15, lq = lane >> 4, kb = lq * 8;

    for (int i = tid; i < 2 * 16 * 392; i += 256) (&hbuf[0][0][0])[i] = (f16)0.0f;

    f16x8 WhF[6][12];
#pragma unroll
    for (int i = 0; i < 6; ++i) {
        const f16* wrow = Wh + (size_t)((w * 6 + i) * 16 + lr) * 384 + kb;
#pragma unroll
        for (int kk = 0; kk < 12; ++kk) WhF[i][kk] = *(const f16x8*)(wrow + kk * 32);
    }
    __syncthreads();

    const int crow = tid >> 4;            // cooperative copy: row, col-base
    const int ccol = (tid & 15) * 8;

    for (int c = 0; c < 128; ++c) {
        wait_flag(flag_pre, c + 1);
        const float* slot = preL + (c & 3) * 24576;
        f32x4 pre_[4][6];
#pragma unroll
        for (int s = 0; s < 4; ++s)
#pragma unroll
            for (int i = 0; i < 6; ++i)
                pre_[s][i] = *(const f32x4*)(slot + ((size_t)(s * 24 + w * 6 + i) * 64 + lane) * 4);

#pragma unroll
        for (int s = 0; s < 4; ++s) {
            const int t = c * 4 + s;      // t parity == s parity (chunk=4)
            f32x4 acc[6];
#pragma unroll
            for (int i = 0; i < 6; ++i) acc[i] = (f32x4){ 0.f, 0.f, 0.f, 0.f };

            const f16* hb = &hbuf[s & 1][0][0] + lr * 392 + kb;
#pragma unroll
            for (int kk = 0; kk < 12; ++kk) {
                const f16x8 a = *(const f16x8*)(hb + kk * 32);
#pragma unroll
                for (int i = 0; i < 6; ++i) acc[i] = MFMA16(a, WhF[i][kk], acc[i]);
            }

            f16* hn = &hbuf[(s + 1) & 1][0][0];
#pragma unroll
            for (int i = 0; i < 6; ++i) {
                const int n = (w * 6 + i) * 16 + lr;
#pragma unroll
                for (int r = 0; r < 4; ++r) {
                    const float v = acc[i][r] + pre_[s][i][r];
                    hn[(lq * 4 + r) * 392 + n] = (f16)fast_tanh(v);
                }
            }
            __syncthreads();
            // coalesced copy h_t -> out_seq (replaces 24 scattered 2B stores/lane)
            const f16* hs = &hbuf[(s + 1) & 1][0][0] + crow * 392 + ccol;
            f16* og = out_seq + (size_t)(t * 16 + crow) * 384 + ccol;
#pragma unroll
            for (int p = 0; p < 3; ++p)
                *(f16x8*)(og + p * 128) = *(const f16x8*)(hs + p * 128);
        }
        set_flag(flag_seq, c + 1);
    }
}

// ---------------- persistent pipeline: 12 blocks (6 A-role + 6 B-role) ----------------
__global__ __launch_bounds__(256, 1) void pipeline_kernel(
    const f16* __restrict__ seq0, const f16* __restrict__ Wi0,
    const f16* __restrict__ WiR, const f16* __restrict__ WhAll,
    const float* __restrict__ biasAll, f16* __restrict__ sA, f16* __restrict__ sB,
    float* __restrict__ preRing, int* __restrict__ flags) {
    __shared__ f16 hbuf[2][16][392];
    const int bid = blockIdx.x;
    // flags[0..5] = seq chunks published by layer l; flags[8..13] = pre chunks published
    if (bid < 6) {
        const int L = bid;
        const f16* in_seq = (L == 0) ? seq0 : ((L & 1) ? sA : sB);
        const f16* Wi = (L == 0) ? Wi0 : (WiR + (size_t)(L - 1) * 384 * 384);
        float* preL = preRing + (size_t)L * 4 * 24576;
        if (L == 0)
            a_role<8>(in_seq, Wi, biasAll, preL, nullptr, flags + 8, flags + 0, 0);
        else
            a_role<12>(in_seq, Wi, biasAll + L * 384, preL, flags + (L - 1), flags + 8 + L, flags + L, L);
    } else {
        const int L = bid - 6;
        f16* outb = (L & 1) ? sB : sA;
        b_role(preRing + (size_t)L * 4 * 24576, WhAll + (size_t)L * 384 * 384, outb,
               flags + 8 + L, flags + L, hbuf);
    }
}

// ---------------- output projection: [8192x384] x [384x32000] + bias ----------------
__global__ __launch_bounds__(256) void out_proj_kernel(
    const f16* __restrict__ A, const f16* __restrict__ Bm,
    const float* __restrict__ bias, float* __restrict__ C) {
    __shared__ f16 As[128][40];
    __shared__ f16 Bs[128][40];
    const int tid = threadIdx.x, lane = tid & 63, w = tid >> 6;
    const int lr = lane & 15, lq = lane >> 4;
    const int bm = blockIdx.x, bn = blockIdx.y;
    const int wm = w >> 1, wn = w & 1;

    f32x4 acc[4][4];
#pragma unroll
    for (int i = 0; i < 4; ++i)
#pragma unroll
        for (int j = 0; j < 4; ++j) acc[i][j] = (f32x4){ 0.f, 0.f, 0.f, 0.f };

    const int sr = tid >> 1, sh = tid & 1;
    const f16* Ag = A + (size_t)(bm * 128 + sr) * 384 + sh * 16;
    const f16* Bg = Bm + (size_t)(bn * 128 + sr) * 384 + sh * 16;

    for (int kt = 0; kt < 12; ++kt) {
        const f16x8 a0 = *(const f16x8*)(Ag + kt * 32);
        const f16x8 a1 = *(const f16x8*)(Ag + kt * 32 + 8);
        const f16x8 b0 = *(const f16x8*)(Bg + kt * 32);
        const f16x8 b1 = *(const f16x8*)(Bg + kt * 32 + 8);
        *(f16x8*)(&As[sr][sh * 16]) = a0;
        *(f16x8*)(&As[sr][sh * 16 + 8]) = a1;
        *(f16x8*)(&Bs[sr][sh * 16]) = b0;
        *(f16x8*)(&Bs[sr][sh * 16 + 8]) = b1;
        __syncthreads();
        f16x8 af[4], bf[4];
#pragma unroll
        for (int mi = 0; mi < 4; ++mi) af[mi] = *(const f16x8*)(&As[wm * 64 + mi * 16 + lr][lq * 8]);
#pragma unroll
        for (int ni = 0; ni < 4; ++ni) bf[ni] = *(const f16x8*)(&Bs[wn * 64 + ni * 16 + lr][lq * 8]);
#pragma unroll
        for (int mi = 0; mi < 4; ++mi)
#pragma unroll
            for (int ni = 0; ni < 4; ++ni) acc[mi][ni] = MFMA16(af[mi], bf[ni], acc[mi][ni]);
        __syncthreads();
    }

    float bv[4];
#pragma unroll
    for (int ni = 0; ni < 4; ++ni) bv[ni] = bias[bn * 128 + wn * 64 + ni * 16 + lr];
#pragma unroll
    for (int mi = 0; mi < 4; ++mi) {
#pragma unroll
        for (int rr = 0; rr < 4; ++rr) {
            const int m = bm * 128 + wm * 64 + mi * 16 + lq * 4 + rr; // token = t*16+b
            const int s = m >> 4, b = m & 15;
            float* crow = C + (size_t)(b * 512 + s) * 32000;
#pragma unroll
            for (int ni = 0; ni < 4; ++ni) {
                const int n = bn * 128 + wn * 64 + ni * 16 + lr;
                crow[n] = acc[mi][ni][rr] + bv[ni];
            }
        }
    }
}

extern "C" void kernel_launch(void* const* d_in, const int* in_sizes, int n_in,
                              void* d_out, int out_size, void* d_ws, size_t ws_size,
                              hipStream_t stream) {
    const int* x = (const int*)d_in[0];
    const float* emb = (const float*)d_in[1];
    const float* W_ih0 = (const float*)d_in[2];
    const float* W_ih = (const float*)d_in[3];
    const float* W_hh = (const float*)d_in[4];
    const float* b_ih = (const float*)d_in[5];
    const float* b_hh = (const float*)d_in[6];
    const float* W_out = (const float*)d_in[7];
    const float* b_out = (const float*)d_in[8];
    float* out = (float*)d_out;

    // workspace layout (bytes)
    char* ws = (char*)d_ws;
    f16* Wi0_h = (f16*)(ws + 0);              //   384*256*2 = 196608
    f16* Wi_h = (f16*)(ws + 196608);          // 5*384*384*2 = 1474560
    f16* Wh_h = (f16*)(ws + 1671168);         // 6*384*384*2 = 1769472
    f16* Wout_h = (f16*)(ws + 3440640);       // 32000*384*2 = 24576000
    float* bias_c = (float*)(ws + 28016640);  // 6*384*4 = 9216
    f16* seq0 = (f16*)(ws + 28025856);        // 8192*256*2 = 4194304
    f16* sA = (f16*)(ws + 32220160);          // 8192*384*2 = 6291456
    f16* sB = (f16*)(ws + 38511616);          // 8192*384*2 = 6291456
    float* preRing = (float*)(ws + 44803072); // 6*4*24576*4 = 2359296
    int* flags = (int*)(ws + 47162368);       // 64*4 = 256 -> end 47162624
    if (ws_size < 47162624u) return;

    hipMemsetAsync(flags, 0, 256, stream);
    cvt_kernel<<<96, 256, 0, stream>>>(W_ih0, Wi0_h, 24576);
    cvt_kernel<<<720, 256, 0, stream>>>(W_ih, Wi_h, 184320);
    cvt_kernel<<<864, 256, 0, stream>>>(W_hh, Wh_h, 221184);
    cvt_kernel<<<12000, 256, 0, stream>>>(W_out, Wout_h, 3072000);
    bias_combine_kernel<<<9, 256, 0, stream>>>(b_ih, b_hh, bias_c);
    embed_kernel<<<8192, 64, 0, stream>>>(x, emb, seq0);

    pipeline_kernel<<<12, 256, 0, stream>>>(seq0, Wi0_h, Wi_h, Wh_h, bias_c,
                                            sA, sB, preRing, flags);

    dim3 g(64, 250);
    out_proj_kernel<<<g, 256, 0, stream>>>(sB, Wout_h, b_out, out);
}

// Round 3
// 1912.768 us; speedup vs baseline: 3.2929x; 1.2043x over previous
//
#include <hip/hip_runtime.h>

typedef _Float16 f16;
typedef _Float16 f16x8 __attribute__((ext_vector_type(8)));
typedef _Float16 f16x4 __attribute__((ext_vector_type(4)));
typedef float f32x4 __attribute__((ext_vector_type(4)));

#define MFMA16(a, b, c) __builtin_amdgcn_mfma_f32_16x16x32_f16(a, b, c, 0, 0, 0)

#define CH 8          // steps per chunk
#define NCH 64        // chunks (512 steps)
#define SLOT_F (CH * 24 * 64 * 4)   // floats per pre-ring slot = 49152

__device__ __forceinline__ float fast_tanh(float x) {
    float e = __builtin_amdgcn_exp2f(x * 2.885390081777927f);
    return 1.0f - 2.0f * __builtin_amdgcn_rcpf(e + 1.0f);
}

// LDS-only barrier: does NOT drain vmcnt (global stores keep flying)
__device__ __forceinline__ void lds_barrier() {
    asm volatile("s_waitcnt lgkmcnt(0)" ::: "memory");
    __builtin_amdgcn_s_barrier();
    __builtin_amdgcn_sched_barrier(0);
}

// ---------------- flag sync (cross-block, agent scope) ----------------
__device__ __forceinline__ void wait_flag(const int* f, int target) {
    if (threadIdx.x == 0) {
        while (__hip_atomic_load(f, __ATOMIC_ACQUIRE, __HIP_MEMORY_SCOPE_AGENT) < target) {
            __builtin_amdgcn_s_sleep(1);
        }
    }
    __syncthreads();
}
__device__ __forceinline__ void set_flag(int* f, int val) {
    __syncthreads();  // drains vmcnt(0): all global stores visible before release
    if (threadIdx.x == 0)
        __hip_atomic_store(f, val, __ATOMIC_RELEASE, __HIP_MEMORY_SCOPE_AGENT);
}

// ---------------- weight convert: f32 -> f16 ----------------
__global__ void cvt_kernel(const float* __restrict__ src, f16* __restrict__ dst, const int n4) {
    const int i = blockIdx.x * blockDim.x + threadIdx.x;
    if (i < n4) {
        const float4 v = ((const float4*)src)[i];
        f16x4 o = { (f16)v.x, (f16)v.y, (f16)v.z, (f16)v.w };
        *(f16x4*)(dst + (size_t)i * 4) = o;
    }
}

__global__ void bias_combine_kernel(const float* __restrict__ b_ih, const float* __restrict__ b_hh,
                                    float* __restrict__ bias_c) {
    const int i = blockIdx.x * blockDim.x + threadIdx.x;
    if (i < 6 * 384) bias_c[i] = b_ih[i] + b_hh[i];
}

// ---------------- embedding gather + cast ----------------
__global__ void embed_kernel(const int* __restrict__ x, const float* __restrict__ emb,
                             f16* __restrict__ seq0) {
    const int token = blockIdx.x;          // token = t*16 + b
    const int s = token >> 4, b = token & 15;
    const int idx = x[b * 512 + s];
    const float4 v = ((const float4*)(emb + (size_t)idx * 256))[threadIdx.x];
    f16x4 o = { (f16)v.x, (f16)v.y, (f16)v.z, (f16)v.w };
    *(f16x4*)(seq0 + (size_t)token * 256 + threadIdx.x * 4) = o;
}

// ---------------- A-role: input projection, Wi register-resident ----------------
template<int NK>
__device__ __forceinline__ void a_role(const f16* __restrict__ in_seq,
                                       const f16* __restrict__ Wi,
                                       const float* __restrict__ bias,
                                       float* __restrict__ preL,
                                       const int* flag_in, int* flag_pre, const int* flag_seq,
                                       const int L) {
    const int tid = threadIdx.x, lane = tid & 63, w = tid >> 6;
    const int lr = lane & 15, lq = lane >> 4;
    const int KIN = NK * 32;

    f16x8 WiF[6][NK];
#pragma unroll
    for (int i = 0; i < 6; ++i) {
        const f16* wrow = Wi + (size_t)((w * 6 + i) * 16 + lr) * KIN + lq * 8;
#pragma unroll
        for (int kk = 0; kk < NK; ++kk) WiF[i][kk] = *(const f16x8*)(wrow + kk * 32);
    }
    float bv[6];
#pragma unroll
    for (int i = 0; i < 6; ++i) bv[i] = bias[(w * 6 + i) * 16 + lr];

    for (int c = 0; c < NCH; ++c) {
        if (L > 0) wait_flag(flag_in, c + 1);          // input chunk ready
        if (c >= 4) wait_flag(flag_seq, c - 3);        // ring back-pressure

        float* slot = preL + (size_t)(c & 3) * SLOT_F;
#pragma unroll
        for (int g = 0; g < 2; ++g) {                  // two 4-step groups per chunk
            f32x4 acc[4][6];
#pragma unroll
            for (int s = 0; s < 4; ++s)
#pragma unroll
                for (int i = 0; i < 6; ++i) acc[s][i] = (f32x4){ bv[i], bv[i], bv[i], bv[i] };

            const int t0 = c * CH + g * 4;
#pragma unroll
            for (int kk = 0; kk < NK; ++kk) {
                f16x8 a[4];
#pragma unroll
                for (int s = 0; s < 4; ++s)
                    a[s] = *(const f16x8*)(in_seq + (size_t)((t0 + s) * 16 + lr) * KIN + kk * 32 + lq * 8);
#pragma unroll
                for (int s = 0; s < 4; ++s)
#pragma unroll
                    for (int i = 0; i < 6; ++i) acc[s][i] = MFMA16(a[s], WiF[i][kk], acc[s][i]);
            }
#pragma unroll
            for (int s = 0; s < 4; ++s)
#pragma unroll
                for (int i = 0; i < 6; ++i)
                    *(f32x4*)(slot + ((size_t)((g * 4 + s) * 24 + w * 6 + i) * 64 + lane) * 4) = acc[s][i];
        }
        set_flag(flag_pre, c + 1);
    }
}

// ---------------- B-role: recurrence, Wh register-resident ----------------
__device__ __forceinline__ void b_role(const float* __restrict__ preL,
                                       const f16* __restrict__ Wh,
                                       f16* __restrict__ out_seq,
                                       const int* flag_pre, int* flag_seq,
                                       f16 (*hbuf)[16][392]) {
    const int tid = threadIdx.x, lane = tid & 63, w = tid >> 6;
    const int lr = lane & 15, lq = lane >> 4, kb = lq * 8;

    for (int i = tid; i < 2 * 16 * 392; i += 256) (&hbuf[0][0][0])[i] = (f16)0.0f;

    f16x8 WhF[6][12];
#pragma unroll
    for (int i = 0; i < 6; ++i) {
        const f16* wrow = Wh + (size_t)((w * 6 + i) * 16 + lr) * 384 + kb;
#pragma unroll
        for (int kk = 0; kk < 12; ++kk) WhF[i][kk] = *(const f16x8*)(wrow + kk * 32);
    }
    __syncthreads();

    const int crow = tid >> 4;            // cooperative copy: row, col-base
    const int ccol = (tid & 15) * 8;

    for (int c = 0; c < NCH; ++c) {
        wait_flag(flag_pre, c + 1);
        const float* slot = preL + (size_t)(c & 3) * SLOT_F;

#pragma unroll
        for (int g = 0; g < 2; ++g) {
            f32x4 pre_[4][6];
#pragma unroll
            for (int s = 0; s < 4; ++s)
#pragma unroll
                for (int i = 0; i < 6; ++i)
                    pre_[s][i] = *(const f32x4*)(slot + ((size_t)((g * 4 + s) * 24 + w * 6 + i) * 64 + lane) * 4);

#pragma unroll
            for (int s4 = 0; s4 < 4; ++s4) {
                const int sc = g * 4 + s4;            // step within chunk
                const int t = c * CH + sc;            // global step; t&1 == sc&1 (CH even)
                f32x4 acc[6];
#pragma unroll
                for (int i = 0; i < 6; ++i) acc[i] = (f32x4){ 0.f, 0.f, 0.f, 0.f };

                const f16* hb = &hbuf[sc & 1][0][0] + lr * 392 + kb;
#pragma unroll
                for (int kk = 0; kk < 12; ++kk) {
                    const f16x8 a = *(const f16x8*)(hb + kk * 32);
#pragma unroll
                    for (int i = 0; i < 6; ++i) acc[i] = MFMA16(a, WhF[i][kk], acc[i]);
                }

                f16* hn = &hbuf[(sc + 1) & 1][0][0];
#pragma unroll
                for (int i = 0; i < 6; ++i) {
                    const int n = (w * 6 + i) * 16 + lr;
#pragma unroll
                    for (int r = 0; r < 4; ++r) {
                        const float v = acc[i][r] + pre_[s4][i][r];
                        hn[(lq * 4 + r) * 392 + n] = (f16)fast_tanh(v);
                    }
                }
                lds_barrier();   // LDS-only: global stores below are NOT drained per step
                const f16* hs = &hbuf[(sc + 1) & 1][0][0] + crow * 392 + ccol;
                f16* og = out_seq + (size_t)(t * 16 + crow) * 384 + ccol;
#pragma unroll
                for (int p = 0; p < 3; ++p)
                    *(f16x8*)(og + p * 128) = *(const f16x8*)(hs + p * 128);
            }
        }
        set_flag(flag_seq, c + 1);   // full __syncthreads drains the chunk's stores
    }
}

// ---------------- persistent pipeline: 12 blocks (6 A-role + 6 B-role) ----------------
__global__ __launch_bounds__(256, 1) void pipeline_kernel(
    const f16* __restrict__ seq0, const f16* __restrict__ Wi0,
    const f16* __restrict__ WiR, const f16* __restrict__ WhAll,
    const float* __restrict__ biasAll, f16* __restrict__ sA, f16* __restrict__ sB,
    float* __restrict__ preRing, int* __restrict__ flags) {
    __shared__ f16 hbuf[2][16][392];
    const int bid = blockIdx.x;
    // flags[0..5] = seq chunks published by layer l; flags[8..13] = pre chunks published
    if (bid < 6) {
        const int L = bid;
        const f16* in_seq = (L == 0) ? seq0 : ((L & 1) ? sA : sB);
        const f16* Wi = (L == 0) ? Wi0 : (WiR + (size_t)(L - 1) * 384 * 384);
        float* preL = preRing + (size_t)L * 4 * SLOT_F;
        if (L == 0)
            a_role<8>(in_seq, Wi, biasAll, preL, nullptr, flags + 8, flags + 0, 0);
        else
            a_role<12>(in_seq, Wi, biasAll + L * 384, preL, flags + (L - 1), flags + 8 + L, flags + L, L);
    } else {
        const int L = bid - 6;
        f16* outb = (L & 1) ? sB : sA;
        b_role(preRing + (size_t)L * 4 * SLOT_F, WhAll + (size_t)L * 384 * 384, outb,
               flags + 8 + L, flags + L, hbuf);
    }
}

// ---------------- output projection: [8192x384] x [384x32000] + bias ----------------
__global__ __launch_bounds__(256) void out_proj_kernel(
    const f16* __restrict__ A, const f16* __restrict__ Bm,
    const float* __restrict__ bias, float* __restrict__ C) {
    __shared__ f16 As[128][40];
    __shared__ f16 Bs[128][40];
    const int tid = threadIdx.x, lane = tid & 63, w = tid >> 6;
    const int lr = lane & 15, lq = lane >> 4;
    const int bm = blockIdx.x, bn = blockIdx.y;
    const int wm = w >> 1, wn = w & 1;

    f32x4 acc[4][4];
#pragma unroll
    for (int i = 0; i < 4; ++i)
#pragma unroll
        for (int j = 0; j < 4; ++j) acc[i][j] = (f32x4){ 0.f, 0.f, 0.f, 0.f };

    const int sr = tid >> 1, sh = tid & 1;
    const f16* Ag = A + (size_t)(bm * 128 + sr) * 384 + sh * 16;
    const f16* Bg = Bm + (size_t)(bn * 128 + sr) * 384 + sh * 16;

    for (int kt = 0; kt < 12; ++kt) {
        const f16x8 a0 = *(const f16x8*)(Ag + kt * 32);
        const f16x8 a1 = *(const f16x8*)(Ag + kt * 32 + 8);
        const f16x8 b0 = *(const f16x8*)(Bg + kt * 32);
        const f16x8 b1 = *(const f16x8*)(Bg + kt * 32 + 8);
        *(f16x8*)(&As[sr][sh * 16]) = a0;
        *(f16x8*)(&As[sr][sh * 16 + 8]) = a1;
        *(f16x8*)(&Bs[sr][sh * 16]) = b0;
        *(f16x8*)(&Bs[sr][sh * 16 + 8]) = b1;
        __syncthreads();
        f16x8 af[4], bf[4];
#pragma unroll
        for (int mi = 0; mi < 4; ++mi) af[mi] = *(const f16x8*)(&As[wm * 64 + mi * 16 + lr][lq * 8]);
#pragma unroll
        for (int ni = 0; ni < 4; ++ni) bf[ni] = *(const f16x8*)(&Bs[wn * 64 + ni * 16 + lr][lq * 8]);
#pragma unroll
        for (int mi = 0; mi < 4; ++mi)
#pragma unroll
            for (int ni = 0; ni < 4; ++ni) acc[mi][ni] = MFMA16(af[mi], bf[ni], acc[mi][ni]);
        __syncthreads();
    }

    float bv[4];
#pragma unroll
    for (int ni = 0; ni < 4; ++ni) bv[ni] = bias[bn * 128 + wn * 64 + ni * 16 + lr];
#pragma unroll
    for (int mi = 0; mi < 4; ++mi) {
#pragma unroll
        for (int rr = 0; rr < 4; ++rr) {
            const int m = bm * 128 + wm * 64 + mi * 16 + lq * 4 + rr; // token = t*16+b
            const int s = m >> 4, b = m & 15;
            float* crow = C + (size_t)(b * 512 + s) * 32000;
#pragma unroll
            for (int ni = 0; ni < 4; ++ni) {
                const int n = bn * 128 + wn * 64 + ni * 16 + lr;
                crow[n] = acc[mi][ni][rr] + bv[ni];
            }
        }
    }
}

extern "C" void kernel_launch(void* const* d_in, const int* in_sizes, int n_in,
                              void* d_out, int out_size, void* d_ws, size_t ws_size,
                              hipStream_t stream) {
    const int* x = (const int*)d_in[0];
    const float* emb = (const float*)d_in[1];
    const float* W_ih0 = (const float*)d_in[2];
    const float* W_ih = (const float*)d_in[3];
    const float* W_hh = (const float*)d_in[4];
    const float* b_ih = (const float*)d_in[5];
    const float* b_hh = (const float*)d_in[6];
    const float* W_out = (const float*)d_in[7];
    const float* b_out = (const float*)d_in[8];
    float* out = (float*)d_out;

    // workspace layout (bytes)
    char* ws = (char*)d_ws;
    f16* Wi0_h = (f16*)(ws + 0);              //   384*256*2 = 196608
    f16* Wi_h = (f16*)(ws + 196608);          // 5*384*384*2 = 1474560
    f16* Wh_h = (f16*)(ws + 1671168);         // 6*384*384*2 = 1769472
    f16* Wout_h = (f16*)(ws + 3440640);       // 32000*384*2 = 24576000
    float* bias_c = (float*)(ws + 28016640);  // 6*384*4 = 9216
    f16* seq0 = (f16*)(ws + 28025856);        // 8192*256*2 = 4194304
    f16* sA = (f16*)(ws + 32220160);          // 8192*384*2 = 6291456
    f16* sB = (f16*)(ws + 38511616);          // 8192*384*2 = 6291456
    float* preRing = (float*)(ws + 44803072); // 6*4*49152*4 = 4718592
    int* flags = (int*)(ws + 49521664);       // 256 -> end 49521920
    if (ws_size < 49521920u) return;

    hipMemsetAsync(flags, 0, 256, stream);
    cvt_kernel<<<96, 256, 0, stream>>>(W_ih0, Wi0_h, 24576);
    cvt_kernel<<<720, 256, 0, stream>>>(W_ih, Wi_h, 184320);
    cvt_kernel<<<864, 256, 0, stream>>>(W_hh, Wh_h, 221184);
    cvt_kernel<<<12000, 256, 0, stream>>>(W_out, Wout_h, 3072000);
    bias_combine_kernel<<<9, 256, 0, stream>>>(b_ih, b_hh, bias_c);
    embed_kernel<<<8192, 64, 0, stream>>>(x, emb, seq0);

    pipeline_kernel<<<12, 256, 0, stream>>>(seq0, Wi0_h, Wi_h, Wh_h, bias_c,
                                            sA, sB, preRing, flags);

    dim3 g(64, 250);
    out_proj_kernel<<<g, 256, 0, stream>>>(sB, Wout_h, b_out, out);
}